// Round 2
// baseline (666.469 us; speedup 1.0000x reference)
//
#include <hip/hip_runtime.h>

// 3D multi-scale deformable attention (fp32), round 2:
// 2 lanes per query × 16 channels per lane (was 8 lanes × 4 ch) to cut
// duplicated per-point setup VALU 4x; branchless clamped corners; nontemporal
// param loads to keep the (n,m) value slice resident in L2.
typedef float f32x4 __attribute__((ext_vector_type(4)));

constexpr int kN  = 2;
constexpr int kS  = 29200;
constexpr int kM  = 8;
constexpr int kD  = 32;
constexpr int kL  = 3;
constexpr int kP  = 4;
constexpr int kLq = 29200;

constexpr int kQPB     = 128;                               // queries per 256-thread block
constexpr int kQChunks = (kLq + kQPB - 1) / kQPB;           // 229
constexpr int kCombos  = kN * kM;                           // 16
constexpr int kBlocks  = kCombos * kQChunks;                // 3664 = 8 * 458

__device__ __forceinline__ f32x4 ntload4(const float* p) {
  return __builtin_nontemporal_load(reinterpret_cast<const f32x4*>(p));
}

__global__ __launch_bounds__(256) void msda3d_kernel(
    const float* __restrict__ value,
    const float* __restrict__ sloc,
    const float* __restrict__ attw,
    float* __restrict__ out)
{
  constexpr int LT[3]   = {16, 8, 4};
  constexpr int LH[3]   = {40, 20, 10};
  constexpr int LW[3]   = {40, 20, 10};
  constexpr int LOFF[3] = {0, 25600, 28800};

  // XCD-aware swizzle: XCD x handles combos {2x, 2x+1} sequentially; each
  // combo's value slice is 3.74 MB (~one XCD's 4 MB L2).
  const int bid    = blockIdx.x;
  const int xcd    = bid & 7;
  const int li     = bid >> 3;                  // 0..457
  const int half   = (li >= kQChunks) ? 1 : 0;
  const int combo  = xcd * 2 + half;            // 0..15
  const int qblock = li - half * kQChunks;      // 0..228
  const int n = combo >> 3;
  const int m = combo & 7;

  const int group = threadIdx.x >> 1;           // 0..127: query within block
  const int lane2 = threadIdx.x & 1;            // 0..1  : channel half (16 ch)
  const int q = qblock * kQPB + group;
  if (q >= kLq) return;

  const size_t qm = (size_t)(n * kLq + q) * kM + m;
  const float* __restrict__ lp = sloc + qm * (kL * kP * 3);   // 36 floats, 16B-aligned
  const float* __restrict__ wp = attw + qm * (kL * kP);       // 12 floats, 16B-aligned
  const float* __restrict__ vb =
      value + ((size_t)n * kS * kM + m) * kD + lane2 * 16;

  f32x4 acc0 = {0.f, 0.f, 0.f, 0.f};
  f32x4 acc1 = {0.f, 0.f, 0.f, 0.f};
  f32x4 acc2 = {0.f, 0.f, 0.f, 0.f};
  f32x4 acc3 = {0.f, 0.f, 0.f, 0.f};

#pragma unroll
  for (int l = 0; l < kL; ++l) {
    const int T = LT[l], H = LH[l], W = LW[l];
    const int base = LOFF[l];

    // Per-level params: 12 coords + 4 weights, nontemporal (streamed once).
    const f32x4 c0 = ntload4(lp + l * 12 + 0);
    const f32x4 c1 = ntload4(lp + l * 12 + 4);
    const f32x4 c2 = ntload4(lp + l * 12 + 8);
    const f32x4 w4 = ntload4(wp + l * 4);
    const float crd[12] = {c0[0], c0[1], c0[2], c0[3],
                           c1[0], c1[1], c1[2], c1[3],
                           c2[0], c2[1], c2[2], c2[3]};
    const float aww[4] = {w4[0], w4[1], w4[2], w4[3]};

#pragma unroll
    for (int p = 0; p < kP; ++p) {
      const float gx = crd[p * 3 + 0];
      const float gy = crd[p * 3 + 1];
      const float gz = crd[p * 3 + 2];
      const float aw = aww[p];

      // align_corners=False unnormalize: x = loc*W - 0.5
      const float x = gx * (float)W - 0.5f;
      const float y = gy * (float)H - 0.5f;
      const float z = gz * (float)T - 0.5f;
      const float xf = floorf(x), yf = floorf(y), zf = floorf(z);
      const float fx = x - xf, fy = y - yf, fz = z - zf;
      const int x0 = (int)xf, y0 = (int)yf, z0 = (int)zf;
      const int x1 = x0 + 1, y1 = y0 + 1, z1 = z0 + 1;
      const bool vx0 = (unsigned)x0 < (unsigned)W;
      const bool vx1 = (unsigned)x1 < (unsigned)W;
      const bool vy0 = (unsigned)y0 < (unsigned)H;
      const bool vy1 = (unsigned)y1 < (unsigned)H;
      const bool vz0 = (unsigned)z0 < (unsigned)T;
      const bool vz1 = (unsigned)z1 < (unsigned)T;
      // Clamped coords (weight is zeroed when invalid, so 0 is fine).
      const int xc0 = vx0 ? x0 : 0, xc1 = vx1 ? x1 : 0;
      const int yc0 = vy0 ? y0 : 0, yc1 = vy1 ? y1 : 0;
      const int zc0 = vz0 ? z0 : 0, zc1 = vz1 ? z1 : 0;
      // Row bases (include level offset).
      const int r00 = base + (zc0 * H + yc0) * W;
      const int r01 = base + (zc0 * H + yc1) * W;
      const int r10 = base + (zc1 * H + yc0) * W;
      const int r11 = base + (zc1 * H + yc1) * W;
      // Weights; attention weight folded into x-lerp.
      const float wx0 = (1.f - fx) * aw, wx1 = fx * aw;
      const float wy0 = 1.f - fy, wy1 = fy;
      const float wz0 = 1.f - fz, wz1 = fz;
      const float w00 = wz0 * wy0, w01 = wz0 * wy1;
      const float w10 = wz1 * wy0, w11 = wz1 * wy1;
      const bool o00 = vz0 && vy0, o01 = vz0 && vy1;
      const bool o10 = vz1 && vy0, o11 = vz1 && vy1;

#define CORNER(r, xc, ok, w_) {                                                \
      const float cw = (ok) ? (w_) : 0.f;                                      \
      const float* vp = vb + (size_t)((r) + (xc)) * (kM * kD);                 \
      const f32x4 v0 = *reinterpret_cast<const f32x4*>(vp);                    \
      const f32x4 v1 = *reinterpret_cast<const f32x4*>(vp + 4);                \
      const f32x4 v2 = *reinterpret_cast<const f32x4*>(vp + 8);                \
      const f32x4 v3 = *reinterpret_cast<const f32x4*>(vp + 12);               \
      acc0 += v0 * cw; acc1 += v1 * cw; acc2 += v2 * cw; acc3 += v3 * cw; }

      CORNER(r00, xc0, o00 && vx0, w00 * wx0)
      CORNER(r00, xc1, o00 && vx1, w00 * wx1)
      CORNER(r01, xc0, o01 && vx0, w01 * wx0)
      CORNER(r01, xc1, o01 && vx1, w01 * wx1)
      CORNER(r10, xc0, o10 && vx0, w10 * wx0)
      CORNER(r10, xc1, o10 && vx1, w10 * wx1)
      CORNER(r11, xc0, o11 && vx0, w11 * wx0)
      CORNER(r11, xc1, o11 && vx1, w11 * wx1)
#undef CORNER
    }
  }

  float* __restrict__ op =
      out + (size_t)(n * kLq + q) * (kM * kD) + m * kD + lane2 * 16;
  *reinterpret_cast<f32x4*>(op + 0)  = acc0;
  *reinterpret_cast<f32x4*>(op + 4)  = acc1;
  *reinterpret_cast<f32x4*>(op + 8)  = acc2;
  *reinterpret_cast<f32x4*>(op + 12) = acc3;
}

extern "C" void kernel_launch(void* const* d_in, const int* in_sizes, int n_in,
                              void* d_out, int out_size, void* d_ws, size_t ws_size,
                              hipStream_t stream) {
  const float* value = (const float*)d_in[0];
  // d_in[1] = value_spatial_shapes (int32) — static, hardcoded above.
  const float* sloc  = (const float*)d_in[2];
  const float* attw  = (const float*)d_in[3];
  float* out = (float*)d_out;

  msda3d_kernel<<<kBlocks, 256, 0, stream>>>(value, sloc, attw, out);
}

// Round 3
// 397.273 us; speedup vs baseline: 1.6776x; 1.6776x over previous
//
#include <hip/hip_runtime.h>

// 3D multi-scale deformable attention (fp32), round 3:
// - 8 lanes x float4 per query (1 load instr per corner; round-1 layout)
// - branchless corners (clamped idx + zeroed weight; no exec-mask branches)
// - per point: compute all 8 offsets/weights, then 8 batched loads, then FMAs
// - u32 byte offsets from SGPR-uniform base (no per-corner 64-bit addr math)
// - nontemporal param loads + output store to protect the value slice in L2
typedef float f32x4 __attribute__((ext_vector_type(4)));

constexpr int kN  = 2;
constexpr int kS  = 29200;
constexpr int kM  = 8;
constexpr int kD  = 32;
constexpr int kL  = 3;
constexpr int kP  = 4;
constexpr int kLq = 29200;

constexpr int kGroups  = 32;                                // queries per block
constexpr int kQChunks = (kLq + kGroups - 1) / kGroups;     // 913
constexpr int kBlocks  = kN * kM * kQChunks;                // 14608 = 8 * 1826

__device__ __forceinline__ f32x4 ntload4(const float* p) {
  return __builtin_nontemporal_load(reinterpret_cast<const f32x4*>(p));
}
__device__ __forceinline__ f32x4 load16(const float* base, unsigned byteoff) {
  return *reinterpret_cast<const f32x4*>(
      reinterpret_cast<const char*>(base) + byteoff);
}

__global__ __launch_bounds__(256) void msda3d_kernel(
    const float* __restrict__ value,
    const float* __restrict__ sloc,
    const float* __restrict__ attw,
    float* __restrict__ out)
{
  constexpr int LT[3]   = {16, 8, 4};
  constexpr int LH[3]   = {40, 20, 10};
  constexpr int LW[3]   = {40, 20, 10};
  constexpr int LOFF[3] = {0, 25600, 28800};

  // XCD-aware swizzle: XCD x handles combos {2x, 2x+1} sequentially; each
  // combo's value slice is 3.74 MB (~one XCD's 4 MB L2).
  const int bid    = blockIdx.x;
  const int xcd    = bid & 7;
  const int li     = bid >> 3;                  // 0..1825
  const int half   = (li >= kQChunks) ? 1 : 0;
  const int combo  = xcd * 2 + half;            // 0..15
  const int qblock = li - half * kQChunks;      // 0..912
  const int n = combo >> 3;
  const int m = combo & 7;

  const int group = threadIdx.x >> 3;           // 0..31: query within block
  const int lane8 = threadIdx.x & 7;            // 0..7 : channel quad
  const int q = qblock * kGroups + group;
  if (q >= kLq) return;

  const size_t qm = (size_t)(n * kLq + q) * kM + m;
  const float* __restrict__ lp = sloc + qm * (kL * kP * 3);   // 36 floats
  const float* __restrict__ wp = attw + qm * (kL * kP);       // 12 floats
  // SGPR-uniform base; lane's channel-quad folded into u32 byte offsets.
  const float* __restrict__ vbase = value + ((size_t)n * kS * kM + m) * kD;
  const unsigned loff = (unsigned)lane8 * 16u;  // bytes

  f32x4 acc = {0.f, 0.f, 0.f, 0.f};

#pragma unroll
  for (int l = 0; l < kL; ++l) {
    const int T = LT[l], H = LH[l], W = LW[l];
    const unsigned ubase = ((unsigned)LOFF[l] << 10) + loff;  // level base, bytes

    const f32x4 c0 = ntload4(lp + l * 12 + 0);
    const f32x4 c1 = ntload4(lp + l * 12 + 4);
    const f32x4 c2 = ntload4(lp + l * 12 + 8);
    const f32x4 w4 = ntload4(wp + l * 4);
    const float crd[12] = {c0[0], c0[1], c0[2], c0[3],
                           c1[0], c1[1], c1[2], c1[3],
                           c2[0], c2[1], c2[2], c2[3]};
    const float aww[4] = {w4[0], w4[1], w4[2], w4[3]};

#pragma unroll
    for (int p = 0; p < kP; ++p) {
      const float gx = crd[p * 3 + 0];
      const float gy = crd[p * 3 + 1];
      const float gz = crd[p * 3 + 2];
      const float aw = aww[p];

      // align_corners=False unnormalize: x = loc*W - 0.5
      const float x = gx * (float)W - 0.5f;
      const float y = gy * (float)H - 0.5f;
      const float z = gz * (float)T - 0.5f;
      const float xf = floorf(x), yf = floorf(y), zf = floorf(z);
      const float fx = x - xf, fy = y - yf, fz = z - zf;
      const int x0 = (int)xf, y0 = (int)yf, z0 = (int)zf;
      const int x1 = x0 + 1, y1 = y0 + 1, z1 = z0 + 1;
      const bool vx0 = (unsigned)x0 < (unsigned)W;
      const bool vx1 = (unsigned)x1 < (unsigned)W;
      const bool vy0 = (unsigned)y0 < (unsigned)H;
      const bool vy1 = (unsigned)y1 < (unsigned)H;
      const bool vz0 = (unsigned)z0 < (unsigned)T;
      const bool vz1 = (unsigned)z1 < (unsigned)T;
      const int xc0 = vx0 ? x0 : 0, xc1 = vx1 ? x1 : 0;
      const int yc0 = vy0 ? y0 : 0, yc1 = vy1 ? y1 : 0;
      const int zc0 = vz0 ? z0 : 0, zc1 = vz1 ? z1 : 0;
      // Row indices (spatial sites) for the 4 (z,y) combos.
      const int r00 = (zc0 * H + yc0) * W;
      const int r01 = (zc0 * H + yc1) * W;
      const int r10 = (zc1 * H + yc0) * W;
      const int r11 = (zc1 * H + yc1) * W;
      // Lerp weights; attention weight folded into x terms.
      const float wx0 = (1.f - fx) * aw, wx1 = fx * aw;
      const float wy0 = 1.f - fy, wy1 = fy;
      const float wz0 = 1.f - fz, wz1 = fz;
      const float w00 = wz0 * wy0, w01 = wz0 * wy1;
      const float w10 = wz1 * wy0, w11 = wz1 * wy1;
      const bool o00 = vz0 && vy0, o01 = vz0 && vy1;
      const bool o10 = vz1 && vy0, o11 = vz1 && vy1;

      // All 8 corner byte-offsets (u32) and masked weights, then 8 loads.
      unsigned off[8];
      float cw[8];
      off[0] = ubase + ((unsigned)(r00 + xc0) << 10);
      off[1] = ubase + ((unsigned)(r00 + xc1) << 10);
      off[2] = ubase + ((unsigned)(r01 + xc0) << 10);
      off[3] = ubase + ((unsigned)(r01 + xc1) << 10);
      off[4] = ubase + ((unsigned)(r10 + xc0) << 10);
      off[5] = ubase + ((unsigned)(r10 + xc1) << 10);
      off[6] = ubase + ((unsigned)(r11 + xc0) << 10);
      off[7] = ubase + ((unsigned)(r11 + xc1) << 10);
      cw[0] = (o00 && vx0) ? w00 * wx0 : 0.f;
      cw[1] = (o00 && vx1) ? w00 * wx1 : 0.f;
      cw[2] = (o01 && vx0) ? w01 * wx0 : 0.f;
      cw[3] = (o01 && vx1) ? w01 * wx1 : 0.f;
      cw[4] = (o10 && vx0) ? w10 * wx0 : 0.f;
      cw[5] = (o10 && vx1) ? w10 * wx1 : 0.f;
      cw[6] = (o11 && vx0) ? w11 * wx0 : 0.f;
      cw[7] = (o11 && vx1) ? w11 * wx1 : 0.f;

      f32x4 v[8];
#pragma unroll
      for (int c = 0; c < 8; ++c) v[c] = load16(vbase, off[c]);
#pragma unroll
      for (int c = 0; c < 8; ++c) acc += v[c] * cw[c];
    }
  }

  float* __restrict__ op =
      out + (size_t)(n * kLq + q) * (kM * kD) + m * kD + lane8 * 4;
  __builtin_nontemporal_store(acc, reinterpret_cast<f32x4*>(op));
}

extern "C" void kernel_launch(void* const* d_in, const int* in_sizes, int n_in,
                              void* d_out, int out_size, void* d_ws, size_t ws_size,
                              hipStream_t stream) {
  const float* value = (const float*)d_in[0];
  // d_in[1] = value_spatial_shapes (int32) — static, hardcoded above.
  const float* sloc  = (const float*)d_in[2];
  const float* attw  = (const float*)d_in[3];
  float* out = (float*)d_out;

  msda3d_kernel<<<kBlocks, 256, 0, stream>>>(value, sloc, attw, out);
}